// Round 7
// baseline (333.013 us; speedup 1.0000x reference)
//
#include <hip/hip_runtime.h>
#include <stdint.h>
#include <math.h>

// B=4, T=2048, D=1024, H=16, DK=64.
// Inputs fp32, output fp32; internal compute bf16 MFMA + fp32 accum.
typedef __attribute__((ext_vector_type(8))) __bf16 bf16x8;
typedef __attribute__((ext_vector_type(4))) __bf16 bf16x4;
typedef __attribute__((ext_vector_type(4))) float f32x4;
typedef __attribute__((ext_vector_type(4))) short short4v;

__device__ __forceinline__ void load_lds16(const void* g, void* l) {
  __builtin_amdgcn_global_load_lds((__attribute__((address_space(1))) void*)(g),
                                   (__attribute__((address_space(3))) void*)(l),
                                   16, 0, 0);
}

__device__ __forceinline__ uint32_t pack_bf2(float a, float b) {
  union { __bf16 h; uint16_t u; } x, y;
  x.h = (__bf16)a; y.h = (__bf16)b;
  return (uint32_t)x.u | ((uint32_t)y.u << 16);
}

__device__ __forceinline__ short4v mk4(uint32_t lo, uint32_t hi) {
  union { uint32_t d[2]; short4v v; } u;
  u.d[0] = lo; u.d[1] = hi;
  return u.v;
}

// 16x16x16 bf16 MFMA: B-operand k-layout (k = fq*4+j) matches the S^T
// C-layout exactly -> P feeds PV with ZERO cross-lane ops.
__device__ __forceinline__ f32x4 mfma16(short4v a, short4v b, f32x4 c) {
#if defined(__has_builtin) && __has_builtin(__builtin_amdgcn_mfma_f32_16x16x16bf16_1k)
  return __builtin_amdgcn_mfma_f32_16x16x16bf16_1k(a, b, c, 0, 0, 0);
#else
  asm volatile("v_mfma_f32_16x16x16_bf16 %0, %1, %2, %0"
               : "+v"(c) : "v"(a), "v"(b));
  return c;
#endif
}

// ---------------- x (fp32) -> bf16 canonical copy ----------------
__global__ __launch_bounds__(256)
void convert_x(const float* __restrict__ xf, __bf16* __restrict__ xb) {
  const size_t i = ((size_t)blockIdx.x * 256 + threadIdx.x) * 8;  // n = 8388608 exact
  const float4 u0 = *(const float4*)(xf + i);
  const float4 u1 = *(const float4*)(xf + i + 4);
  bf16x8 v;
  v[0] = (__bf16)u0.x; v[1] = (__bf16)u0.y; v[2] = (__bf16)u0.z; v[3] = (__bf16)u0.w;
  v[4] = (__bf16)u1.x; v[5] = (__bf16)u1.y; v[6] = (__bf16)u1.z; v[7] = (__bf16)u1.w;
  *(bf16x8*)&xb[i] = v;
}

// ---------------- weight transpose ([K,N] fp32 -> [N,K] bf16) + bias pack ----------------
__global__ __launch_bounds__(256)
void prep_weights(const float* __restrict__ Wq, const float* __restrict__ Wk,
                  const float* __restrict__ Wv, const float* __restrict__ Wo,
                  const float* __restrict__ bq, const float* __restrict__ bk,
                  const float* __restrict__ bv, const float* __restrict__ bo,
                  __bf16* __restrict__ Bt1, __bf16* __restrict__ Bt2,
                  float* __restrict__ bqkv, float* __restrict__ bo_f) {
  const int m = blockIdx.z;  // 0=Wq 1=Wk 2=Wv 3=Wo
  const float* W = (m == 0) ? Wq : (m == 1) ? Wk : (m == 2) ? Wv : Wo;
  __bf16* Out = (m == 3) ? Bt2 : Bt1 + (size_t)m * 1024 * 1024;
  const int kt = blockIdx.x * 64, nt = blockIdx.y * 64;
  __shared__ __bf16 tile[64 * 68];
  const int t = threadIdx.x;
#pragma unroll
  for (int i = 0; i < 16; i++) {
    int e = i * 256 + t;
    int r = e >> 6, c = e & 63;
    tile[r * 68 + c] = (__bf16)W[(size_t)(kt + r) * 1024 + nt + c];
  }
  __syncthreads();
#pragma unroll
  for (int i = 0; i < 16; i++) {
    int e = i * 256 + t;
    int r = e >> 6, c = e & 63;
    Out[(size_t)(nt + r) * 1024 + kt + c] = tile[c * 68 + r];
  }
  if (blockIdx.x == 0 && blockIdx.y == 0) {
    if (m < 3) {
      const float* bsrc = (m == 0) ? bq : (m == 1) ? bk : bv;
      for (int i = t; i < 1024; i += 256) bqkv[m * 1024 + i] = bsrc[i];
    } else {
      for (int i = t; i < 1024; i += 256) bo_f[i] = bo[i];
    }
  }
}

// ---------------- GEMM 256x256: C[M,N] = A[M,K] @ Bt[N,K]^T + bias[N] ----------------
// T3+T4 counted-vmcnt schedule (catalog 256-sq template, 2-phase variant):
// 512 thr / 8 waves (2Mx4N), per-wave 128x64 output (acc 8x4xf32x4 = 128 VGPR),
// BK=64, LDS 128KB double-buffered, staged by global_load_lds w=16 with
// PRE-SWIZZLED source slot (slot ^= row&7, 16B slots) -> linear LDS dest
// (rule 21) and conflict-free swizzled b128 frag reads (T2, flash-proven).
// KEY vs m97: next K-tile's 8 loads are issued BEFORE the wait, and the wait
// is s_waitcnt vmcnt(8) -- the 8 new loads stay in flight across BOTH raw
// s_barriers and the whole MFMA phase. __syncthreads is NOT used (it would
// re-insert the vmcnt(0) drain that caps the m97 structure).
__global__ __launch_bounds__(512)
void gemm256(const __bf16* __restrict__ A, const __bf16* __restrict__ Bt,
             const float* __restrict__ bias, void* __restrict__ Cv,
             int out_f32, int M, int N, int K) {
  __shared__ __align__(16) __bf16 As[2][256 * 64];
  __shared__ __align__(16) __bf16 Bs[2][256 * 64];
  const int t = threadIdx.x, lane = t & 63, wave = t >> 6;
  const int wm = wave >> 2, wn = wave & 3;
  const int fm = lane & 15, fq = lane >> 4;
  const int bm = blockIdx.x * 256, bn = blockIdx.y * 256;

  // staging: issue i covers rows i*64 + (t>>3); 8 threads/row, slot = t&7;
  // source k-slot pre-swizzled so LDS[row][slot] = G[row][slot ^ (row&7)]
  const int srow = t >> 3;
  const int scol = ((t & 7) ^ (srow & 7)) << 3;  // elems
  const __bf16* Ag = A + (size_t)(bm + srow) * K + scol;
  const __bf16* Bg = Bt + (size_t)(bn + srow) * K + scol;
  const size_t rstep = (size_t)64 * K;

  f32x4 acc[8][4] = {};
  const int nkt = K >> 6;
  int cur = 0;

#define GSTAGE(KT, BUF)                                                   \
  {                                                                       \
    const size_t ko = (size_t)(KT) * 64;                                  \
    load_lds16(Ag + ko,             &As[BUF][t * 8]);                     \
    load_lds16(Ag + ko + rstep,     &As[BUF][4096 + t * 8]);              \
    load_lds16(Ag + ko + 2 * rstep, &As[BUF][8192 + t * 8]);              \
    load_lds16(Ag + ko + 3 * rstep, &As[BUF][12288 + t * 8]);             \
    load_lds16(Bg + ko,             &Bs[BUF][t * 8]);                     \
    load_lds16(Bg + ko + rstep,     &Bs[BUF][4096 + t * 8]);              \
    load_lds16(Bg + ko + 2 * rstep, &Bs[BUF][8192 + t * 8]);              \
    load_lds16(Bg + ko + 3 * rstep, &Bs[BUF][12288 + t * 8]);             \
  }

  GSTAGE(0, 0);
  for (int kt = 0; kt < nkt; kt++) {
    if (kt + 1 < nkt) {
      GSTAGE(kt + 1, cur ^ 1);  // 8 loads fly across barriers + compute
      asm volatile("s_waitcnt vmcnt(8)" ::: "memory");  // tile kt landed
    } else {
      asm volatile("s_waitcnt vmcnt(0)" ::: "memory");
    }
    __builtin_amdgcn_s_barrier();          // staging of buf[cur] visible
    __builtin_amdgcn_sched_barrier(0);
    const __bf16* Ac = As[cur];
    const __bf16* Bc = Bs[cur];
#pragma unroll
    for (int ks = 0; ks < 2; ks++) {
      bf16x8 af[8], bf[4];
#pragma unroll
      for (int mi = 0; mi < 8; mi++) {
        const int row = wm * 128 + mi * 16 + fm;
        af[mi] = *(const bf16x8*)&Ac[row * 64 + ((((ks << 2) | fq) ^ (fm & 7)) << 3)];
      }
#pragma unroll
      for (int ni = 0; ni < 4; ni++) {
        const int row = wn * 64 + ni * 16 + fm;
        bf[ni] = *(const bf16x8*)&Bc[row * 64 + ((((ks << 2) | fq) ^ (fm & 7)) << 3)];
      }
      __builtin_amdgcn_s_setprio(1);
#pragma unroll
      for (int mi = 0; mi < 8; mi++)
#pragma unroll
        for (int ni = 0; ni < 4; ni++)
          acc[mi][ni] = __builtin_amdgcn_mfma_f32_16x16x32_bf16(af[mi], bf[ni],
                                                                acc[mi][ni], 0, 0, 0);
      __builtin_amdgcn_s_setprio(0);
    }
    __builtin_amdgcn_sched_barrier(0);
    __builtin_amdgcn_s_barrier();  // all reads of buf[cur] done before overwrite
    cur ^= 1;
  }
#undef GSTAGE

  // epilogue: C[row][col], row = bm+wm*128+mi*16+fq*4+r, col = bn+wn*64+ni*16+fm
#pragma unroll
  for (int ni = 0; ni < 4; ni++) {
    const int col = bn + wn * 64 + ni * 16 + fm;
    const float bvv = bias[col];
#pragma unroll
    for (int mi = 0; mi < 8; mi++)
#pragma unroll
      for (int r = 0; r < 4; r++) {
        const int row = bm + wm * 128 + mi * 16 + fq * 4 + r;
        const float val = acc[mi][ni][r] + bvv;
        if (out_f32) ((float*)Cv)[(size_t)row * N + col] = val;
        else ((__bf16*)Cv)[(size_t)row * N + col] = (__bf16)val;
      }
  }
}

// ---------------- V transpose: QKV cols[2048:3072) -> Vt[B,H,DK,T] ----------------
__global__ __launch_bounds__(256)
void transpose_v(const __bf16* __restrict__ QKV, __bf16* __restrict__ Vt) {
  const int tt = blockIdx.x;
  const int bh = blockIdx.y;
  const int b = bh >> 4, h = bh & 15;
  __shared__ __bf16 tile[64 * 68];
  const int t = threadIdx.x;
#pragma unroll
  for (int i = 0; i < 16; i++) {
    int e = i * 256 + t;
    int tok = e >> 6, dk = e & 63;
    tile[tok * 68 + dk] =
        QKV[((size_t)b * 2048 + tt * 64 + tok) * 3072 + 2048 + h * 64 + dk];
  }
  __syncthreads();
#pragma unroll
  for (int i = 0; i < 16; i++) {
    int e = i * 256 + t;
    int dk = e >> 6, tok = e & 63;
    Vt[((size_t)bh * 64 + dk) * 2048 + tt * 64 + tok] = tile[tok * 68 + dk];
  }
}

// ---------------- flash attention, causal, DK=64 (unchanged from r6) ----------------
__global__ __launch_bounds__(512)
void flash_attn(const __bf16* __restrict__ QKV, const __bf16* __restrict__ Vt,
                __bf16* __restrict__ O) {
  const int y = blockIdx.y;            // 0..7
  const int p = (y < 4) ? y : 11 - y;  // pair class 0..7
  const int qhi = 15 - p, qlo = p;     // 128-row tile indices
  const int bh = blockIdx.x;
  const int b = bh >> 4, h = bh & 15;
  __shared__ __align__(16) __bf16 Ks[2][64 * 64];
  __shared__ __align__(16) __bf16 Vs[2][64 * 64];
  const int t = threadIdx.x, lane = t & 63, wave = t >> 6;  // wave 0..7
  const int fm = lane & 15, fq = lane >> 4;
  const int tok0 = t >> 3;  // 0..63: full 64-row tile in ONE load per tensor
  const int csw = ((t & 7) ^ (tok0 & 7)) << 3;  // elems
  const int swb = (fm & 7) << 4;
  const int rb0 = (((fq << 4)) ^ swb) >> 1;       // elems
  const int rb1 = ((64 + (fq << 4)) ^ swb) >> 1;  // elems
  int voff[4];
#pragma unroll
  for (int nt = 0; nt < 4; nt++)
    voff[nt] = (((((nt << 1) | (fq >> 1))) ^ (fm & 7)) << 3) | ((fq & 1) << 2);

  const size_t kbase = ((size_t)b * 2048) * 3072 + 1024 + h * 64;
  const size_t vbase = (size_t)bh * 64 * 2048;
  const int nkt = 2 * qhi + 2;
  const int qmin[2] = {qhi * 128 + wave * 16, qlo * 128 + wave * 16};
  const float SC = 0.18033688011112042f;    // log2(e)/sqrt(64)
  const float THR_RAW = 44.3614195558365f;  // 8 / SC

  bf16x8 qf[2][2];
#pragma unroll
  for (int mi = 0; mi < 2; mi++) {
    const size_t qrow = ((size_t)b * 2048 + qmin[mi] + fm) * 3072 + h * 64;
    qf[mi][0] = *(const bf16x8*)&QKV[qrow + fq * 8];
    qf[mi][1] = *(const bf16x8*)&QKV[qrow + 32 + fq * 8];
  }

  const short4v ones4 = {(short)0x3F80, (short)0x3F80, (short)0x3F80, (short)0x3F80};

  f32x4 o_acc[2][4] = {};
  float m_i[2] = {-1e30f, -1e30f}, l_i[2] = {0.f, 0.f};

#define STAGE(KT, BUF)                                                          \
  {                                                                             \
    const int kb2 = (KT) * 64;                                                  \
    load_lds16(&QKV[kbase + (size_t)(kb2 + tok0) * 3072 + csw],                 \
               &Ks[BUF][t * 8]);                                                \
    load_lds16(&Vt[vbase + (size_t)tok0 * 2048 + kb2 + csw],                    \
               &Vs[BUF][t * 8]);                                                \
  }

  STAGE(0, 0);
  __syncthreads();  // drain + visibility for tile 0
  int cur = 0;

  for (int kt = 0; kt < nkt; kt++) {
    const int kb = kt * 64;
    if (kt + 1 < nkt) STAGE(kt + 1, cur ^ 1);  // flies across this compute

    const bool act0 = (kb <= qmin[0] + 15);
    const bool act1 = (kb <= qmin[1] + 15);
    if (act0) {
      const __bf16* Kc = Ks[cur];
      const __bf16* Vc = Vs[cur];

      f32x4 s[2][4];
      __builtin_amdgcn_s_setprio(1);
#pragma unroll
      for (int nt = 0; nt < 4; nt++) {
        const bf16x8 kf0 = *(const bf16x8*)&Kc[(nt * 16 + fm) * 64 + rb0];
        const bf16x8 kf1 = *(const bf16x8*)&Kc[(nt * 16 + fm) * 64 + rb1];
        {
          f32x4 z = {};
          z = __builtin_amdgcn_mfma_f32_16x16x32_bf16(kf0, qf[0][0], z, 0, 0, 0);
          z = __builtin_amdgcn_mfma_f32_16x16x32_bf16(kf1, qf[0][1], z, 0, 0, 0);
          s[0][nt] = z;
        }
        if (act1) {
          f32x4 z = {};
          z = __builtin_amdgcn_mfma_f32_16x16x32_bf16(kf0, qf[1][0], z, 0, 0, 0);
          z = __builtin_amdgcn_mfma_f32_16x16x32_bf16(kf1, qf[1][1], z, 0, 0, 0);
          s[1][nt] = z;
        }
      }
      __builtin_amdgcn_s_setprio(0);

#pragma unroll
      for (int mi = 0; mi < 2; mi++) {
        if (mi == 1 && !act1) continue;
        if (kb + 63 > qmin[mi]) {
          const int qq = qmin[mi] + fm;
#pragma unroll
          for (int nt = 0; nt < 4; nt++) {
            const int kk = kb + nt * 16 + fq * 4;
#pragma unroll
            for (int r = 0; r < 4; r++)
              if (kk + r > qq) s[mi][nt][r] = -1e30f;
          }
        }
      }

#pragma unroll
      for (int mi = 0; mi < 2; mi++) {
        if (mi == 1 && !act1) continue;

        float a = fmaxf(fmaxf(s[mi][0][0], s[mi][0][1]),
                        fmaxf(s[mi][0][2], s[mi][0][3]));
#pragma unroll
        for (int nt = 1; nt < 4; nt++)
          a = fmaxf(a, fmaxf(fmaxf(s[mi][nt][0], s[mi][nt][1]),
                             fmaxf(s[mi][nt][2], s[mi][nt][3])));
        a = fmaxf(a, __shfl_xor(a, 16, 64));
        a = fmaxf(a, __shfl_xor(a, 32, 64));
        const float rmax = a;

        if (!__all(rmax - m_i[mi] <= THR_RAW)) {
          const float mn = fmaxf(m_i[mi], rmax);
          const float al = exp2f(SC * (m_i[mi] - mn));
          m_i[mi] = mn;
          l_i[mi] *= al;
#pragma unroll
          for (int dt = 0; dt < 4; dt++)
#pragma unroll
            for (int r = 0; r < 4; r++) o_acc[mi][dt][r] *= al;
        }

        short4v pb[4];
        const float msc = -SC * m_i[mi];
#pragma unroll
        for (int nt = 0; nt < 4; nt++) {
          const float p0 = exp2f(fmaf(s[mi][nt][0], SC, msc));
          const float p1 = exp2f(fmaf(s[mi][nt][1], SC, msc));
          const float p2 = exp2f(fmaf(s[mi][nt][2], SC, msc));
          const float p3 = exp2f(fmaf(s[mi][nt][3], SC, msc));
          pb[nt] = mk4(pack_bf2(p0, p1), pack_bf2(p2, p3));
        }

        f32x4 rs = {};
#pragma unroll
        for (int nt = 0; nt < 4; nt++) rs = mfma16(ones4, pb[nt], rs);

        __builtin_amdgcn_s_setprio(1);
#pragma unroll
        for (int dt = 0; dt < 4; dt++) {
          const int rowb = (dt * 16 + fm) * 64;
          f32x4 o = o_acc[mi][dt];
#pragma unroll
          for (int nt = 0; nt < 4; nt++) {
            const short4v vf = *(const short4v*)&Vc[rowb + voff[nt]];
            o = mfma16(vf, pb[nt], o);
          }
          o_acc[mi][dt] = o;
        }
        __builtin_amdgcn_s_setprio(0);

        l_i[mi] += rs[0];
      }
    }

    __syncthreads();  // next tile staged + all reads of buf[cur] complete
    cur ^= 1;
  }

#pragma unroll
  for (int mi = 0; mi < 2; mi++) {
    const float linv = 1.f / l_i[mi];
    const size_t orow = (size_t)b * 2048 + qmin[mi] + fm;
#pragma unroll
    for (int dt = 0; dt < 4; dt++) {
      bf16x4 w;
#pragma unroll
      for (int r = 0; r < 4; r++) w[r] = (__bf16)(o_acc[mi][dt][r] * linv);
      *(bf16x4*)&O[orow * 1024 + h * 64 + dt * 16 + fq * 4] = w;
    }
  }
#undef STAGE
}

// ---------------- launch ----------------
extern "C" void kernel_launch(void* const* d_in, const int* in_sizes, int n_in,
                              void* d_out, int out_size, void* d_ws, size_t ws_size,
                              hipStream_t stream) {
  const float* x = (const float*)d_in[0];
  const float* Wq = (const float*)d_in[1];
  const float* bq = (const float*)d_in[2];
  const float* Wk = (const float*)d_in[3];
  const float* bk = (const float*)d_in[4];
  const float* Wv = (const float*)d_in[5];
  const float* bv = (const float*)d_in[6];
  const float* Wo = (const float*)d_in[7];
  const float* bo = (const float*)d_in[8];

  // workspace layout (bytes), ~92 MB total
  char* ws = (char*)d_ws;
  __bf16* Bt1 = (__bf16*)(ws);               // [3072,1024] WqT|WkT|WvT  (6 MB)
  __bf16* Bt2 = (__bf16*)(ws + 6291456);     // [1024,1024] WoT          (2 MB)
  float* bqkv = (float*)(ws + 8388608);      // [3072] f32
  float* bo_f = (float*)(ws + 8400896);      // [1024] f32
  __bf16* QKV = (__bf16*)(ws + 8405504);     // [8192,3072]              (48 MB)
  __bf16* Vt = (__bf16*)(ws + 58737152);     // [4,16,64,2048]           (16 MB)
  __bf16* Xb = (__bf16*)(ws + 75514368);     // [8192,1024] bf16 x       (16 MB)
  __bf16* Ow = Xb;  // Xb dead after gemm1; flash output reuses the region

  hipLaunchKernelGGL(convert_x, dim3(4096), dim3(256), 0, stream, x, Xb);
  hipLaunchKernelGGL(prep_weights, dim3(16, 16, 4), dim3(256), 0, stream,
                     Wq, Wk, Wv, Wo, bq, bk, bv, bo, Bt1, Bt2, bqkv, bo_f);
  hipLaunchKernelGGL(gemm256, dim3(32, 12), dim3(512), 0, stream,
                     Xb, Bt1, bqkv, (void*)QKV, 0, 8192, 3072, 1024);
  hipLaunchKernelGGL(transpose_v, dim3(32, 64), dim3(256), 0, stream, QKV, Vt);
  hipLaunchKernelGGL(flash_attn, dim3(64, 8), dim3(512), 0, stream, QKV, Vt, Ow);
  hipLaunchKernelGGL(gemm256, dim3(32, 4), dim3(512), 0, stream,
                     Ow, Bt2, bo_f, d_out, 1, 8192, 1024, 1024);
}

// Round 8
// 323.541 us; speedup vs baseline: 1.0293x; 1.0293x over previous
//
#include <hip/hip_runtime.h>
#include <stdint.h>
#include <math.h>

// B=4, T=2048, D=1024, H=16, DK=64.
// Inputs fp32, output fp32; internal compute bf16 MFMA + fp32 accum.
typedef __attribute__((ext_vector_type(8))) __bf16 bf16x8;
typedef __attribute__((ext_vector_type(4))) __bf16 bf16x4;
typedef __attribute__((ext_vector_type(4))) float f32x4;
typedef __attribute__((ext_vector_type(4))) short short4v;

__device__ __forceinline__ void load_lds16(const void* g, void* l) {
  __builtin_amdgcn_global_load_lds((__attribute__((address_space(1))) void*)(g),
                                   (__attribute__((address_space(3))) void*)(l),
                                   16, 0, 0);
}

__device__ __forceinline__ uint32_t pack_bf2(float a, float b) {
  union { __bf16 h; uint16_t u; } x, y;
  x.h = (__bf16)a; y.h = (__bf16)b;
  return (uint32_t)x.u | ((uint32_t)y.u << 16);
}

__device__ __forceinline__ short4v mk4(uint32_t lo, uint32_t hi) {
  union { uint32_t d[2]; short4v v; } u;
  u.d[0] = lo; u.d[1] = hi;
  return u.v;
}

// 16x16x16 bf16 MFMA: B-operand k-layout (k = fq*4+j) matches the S^T
// C-layout exactly -> P feeds PV with ZERO cross-lane ops.
__device__ __forceinline__ f32x4 mfma16(short4v a, short4v b, f32x4 c) {
#if defined(__has_builtin) && __has_builtin(__builtin_amdgcn_mfma_f32_16x16x16bf16_1k)
  return __builtin_amdgcn_mfma_f32_16x16x16bf16_1k(a, b, c, 0, 0, 0);
#else
  asm volatile("v_mfma_f32_16x16x16_bf16 %0, %1, %2, %0"
               : "+v"(c) : "v"(a), "v"(b));
  return c;
#endif
}

// ---------------- x (fp32) -> bf16 canonical copy ----------------
__global__ __launch_bounds__(256)
void convert_x(const float* __restrict__ xf, __bf16* __restrict__ xb) {
  const size_t i = ((size_t)blockIdx.x * 256 + threadIdx.x) * 8;  // n = 8388608 exact
  const float4 u0 = *(const float4*)(xf + i);
  const float4 u1 = *(const float4*)(xf + i + 4);
  bf16x8 v;
  v[0] = (__bf16)u0.x; v[1] = (__bf16)u0.y; v[2] = (__bf16)u0.z; v[3] = (__bf16)u0.w;
  v[4] = (__bf16)u1.x; v[5] = (__bf16)u1.y; v[6] = (__bf16)u1.z; v[7] = (__bf16)u1.w;
  *(bf16x8*)&xb[i] = v;
}

// ---------------- weight transpose ([K,N] fp32 -> [N,K] bf16) + bias pack ----------------
__global__ __launch_bounds__(256)
void prep_weights(const float* __restrict__ Wq, const float* __restrict__ Wk,
                  const float* __restrict__ Wv, const float* __restrict__ Wo,
                  const float* __restrict__ bq, const float* __restrict__ bk,
                  const float* __restrict__ bv, const float* __restrict__ bo,
                  __bf16* __restrict__ Bt1, __bf16* __restrict__ Bt2,
                  float* __restrict__ bqkv, float* __restrict__ bo_f) {
  const int m = blockIdx.z;  // 0=Wq 1=Wk 2=Wv 3=Wo
  const float* W = (m == 0) ? Wq : (m == 1) ? Wk : (m == 2) ? Wv : Wo;
  __bf16* Out = (m == 3) ? Bt2 : Bt1 + (size_t)m * 1024 * 1024;
  const int kt = blockIdx.x * 64, nt = blockIdx.y * 64;
  __shared__ __bf16 tile[64 * 68];
  const int t = threadIdx.x;
#pragma unroll
  for (int i = 0; i < 16; i++) {
    int e = i * 256 + t;
    int r = e >> 6, c = e & 63;
    tile[r * 68 + c] = (__bf16)W[(size_t)(kt + r) * 1024 + nt + c];
  }
  __syncthreads();
#pragma unroll
  for (int i = 0; i < 16; i++) {
    int e = i * 256 + t;
    int r = e >> 6, c = e & 63;
    Out[(size_t)(nt + r) * 1024 + kt + c] = tile[c * 68 + r];
  }
  if (blockIdx.x == 0 && blockIdx.y == 0) {
    if (m < 3) {
      const float* bsrc = (m == 0) ? bq : (m == 1) ? bk : bv;
      for (int i = t; i < 1024; i += 256) bqkv[m * 1024 + i] = bsrc[i];
    } else {
      for (int i = t; i < 1024; i += 256) bo_f[i] = bo[i];
    }
  }
}

// ---------------- GEMM 256x256, 8-phase counted-vmcnt (T3+T4) ----------------
// 512 thr / 8 waves (2Mx4N), per-wave C 128x64, BK=64, LDS 128KB dbuf,
// XOR-swizzled via pre-swizzled global_load_lds source (T2, rule 21).
// Per K-tile j (buf c=j&1), 4 phases, each {ds-reads || 2 gload_lds ->
// s_barrier -> 16 MFMA -> s_barrier}; counted vmcnt(4) ONLY at tile
// boundaries (r7's 2-phase + vmcnt drain was the regression; this is the
// catalog's proven schedule). Region-liveness-safe staggering:
//  ph0: read af[0-3]k0+bf k0 ; stage A-units 0,2 of tile j+1 -> buf[c^1]
//  ph1: read af[0-3]k1+bf k1 ; stage A-units 1,3 of tile j+1
//  ph2: read af[4-7]k0 (bf reg-cached) ; stage B-units 0,1 of tile j+2 -> buf[c]
//       (legal: ALL B reads of tile j closed by ph1's barrier)
//  ph3: read af[4-7]k1 ; stage B-units 2,3 of tile j+2 ; vmcnt(4) ; barrier
// FIFO: wait-to-<=4 at each boundary lands tile j+1 and leaves exactly
// tile j+2's 4 B-loads in flight. Prologue: tile0 (8 units) + B(1) (4),
// vmcnt(4). Epilogue boundaries use vmcnt(0) when no trailing loads.
__global__ __launch_bounds__(512)
void gemm256(const __bf16* __restrict__ A, const __bf16* __restrict__ Bt,
             const float* __restrict__ bias, void* __restrict__ Cv,
             int out_f32, int M, int N, int K) {
  __shared__ __align__(16) __bf16 As[2][256 * 64];
  __shared__ __align__(16) __bf16 Bs[2][256 * 64];
  const int t = threadIdx.x, lane = t & 63, wave = t >> 6;
  const int wm = wave >> 2, wn = wave & 3;
  const int fm = lane & 15, fq = lane >> 4;
  const int bm = blockIdx.x * 256, bn = blockIdx.y * 256;

  // staging unit = 64 rows x 64 k = one gload_lds (512 thr x 16B).
  // thread t: row-in-unit = t>>3, slot = t&7; source slot pre-swizzled so
  // LDS[row][slot] = G[row][slot ^ (row&7)]  (16B slots).
  const int srow = t >> 3;
  const int scol = ((t & 7) ^ (srow & 7)) << 3;  // elems
  const __bf16* Ag = A + (size_t)(bm + srow) * K + scol;
  const __bf16* Bg = Bt + (size_t)(bn + srow) * K + scol;

  // read-side swizzled column offsets (elems) for k-slice ks: rows === fm mod 8
  const int kc0 = ((fq ^ (fm & 7)) << 3);
  const int kc1 = (((4 | fq) ^ (fm & 7)) << 3);

  f32x4 acc[8][4] = {};
  const int nkt = K >> 6;

#define SA_UNIT(TT, BUF, U)                                                  \
  load_lds16(Ag + (size_t)(U) * 64 * K + (size_t)(TT) * 64,                  \
             &As[BUF][(U) * 4096 + t * 8])
#define SB_UNIT(TT, BUF, U)                                                  \
  load_lds16(Bg + (size_t)(U) * 64 * K + (size_t)(TT) * 64,                  \
             &Bs[BUF][(U) * 4096 + t * 8])

  // prologue: tile 0 fully + B of tile 1; wait tile0 (4 B(1) loads fly)
  SA_UNIT(0, 0, 0); SA_UNIT(0, 0, 1); SA_UNIT(0, 0, 2); SA_UNIT(0, 0, 3);
  SB_UNIT(0, 0, 0); SB_UNIT(0, 0, 1); SB_UNIT(0, 0, 2); SB_UNIT(0, 0, 3);
  if (nkt > 1) {
    SB_UNIT(1, 1, 0); SB_UNIT(1, 1, 1); SB_UNIT(1, 1, 2); SB_UNIT(1, 1, 3);
    asm volatile("s_waitcnt vmcnt(4)" ::: "memory");
  } else {
    asm volatile("s_waitcnt vmcnt(0)" ::: "memory");
  }
  __builtin_amdgcn_s_barrier();

  for (int j = 0; j < nkt; ++j) {
    const int c = j & 1;
    const __bf16* Ac = As[c];
    const __bf16* Bc = Bs[c];
    const int ar0 = (wm * 128 + fm) * 64;      // + mi*16*64
    const int br0 = (wn * 64 + fm) * 64;       // + ni*16*64
    bf16x8 afl[4], afh[4], bf0[4], bf1[4];

    // ---- phase 0: af[0-3] k0 + bf k0 ; stage A(j+1) units 0,2 ----
#pragma unroll
    for (int mi = 0; mi < 4; mi++) afl[mi] = *(const bf16x8*)&Ac[ar0 + mi * 1024 + kc0];
#pragma unroll
    for (int ni = 0; ni < 4; ni++) bf0[ni] = *(const bf16x8*)&Bc[br0 + ni * 1024 + kc0];
    if (j + 1 < nkt) { SA_UNIT(j + 1, c ^ 1, 0); SA_UNIT(j + 1, c ^ 1, 2); }
    __builtin_amdgcn_s_barrier();
    __builtin_amdgcn_s_setprio(1);
#pragma unroll
    for (int mi = 0; mi < 4; mi++)
#pragma unroll
      for (int ni = 0; ni < 4; ni++)
        acc[mi][ni] = __builtin_amdgcn_mfma_f32_16x16x32_bf16(afl[mi], bf0[ni],
                                                              acc[mi][ni], 0, 0, 0);
    __builtin_amdgcn_s_setprio(0);
    __builtin_amdgcn_s_barrier();

    // ---- phase 1: af[0-3] k1 + bf k1 ; stage A(j+1) units 1,3 ----
#pragma unroll
    for (int mi = 0; mi < 4; mi++) afl[mi] = *(const bf16x8*)&Ac[ar0 + mi * 1024 + kc1];
#pragma unroll
    for (int ni = 0; ni < 4; ni++) bf1[ni] = *(const bf16x8*)&Bc[br0 + ni * 1024 + kc1];
    if (j + 1 < nkt) { SA_UNIT(j + 1, c ^ 1, 1); SA_UNIT(j + 1, c ^ 1, 3); }
    __builtin_amdgcn_s_barrier();
    __builtin_amdgcn_s_setprio(1);
#pragma unroll
    for (int mi = 0; mi < 4; mi++)
#pragma unroll
      for (int ni = 0; ni < 4; ni++)
        acc[mi][ni] = __builtin_amdgcn_mfma_f32_16x16x32_bf16(afl[mi], bf1[ni],
                                                              acc[mi][ni], 0, 0, 0);
    __builtin_amdgcn_s_setprio(0);
    __builtin_amdgcn_s_barrier();

    // ---- phase 2: af[4-7] k0 (bf0 reg-cached) ; stage B(j+2) units 0,1 ----
#pragma unroll
    for (int mi = 0; mi < 4; mi++)
      afh[mi] = *(const bf16x8*)&Ac[ar0 + (mi + 4) * 1024 + kc0];
    if (j + 2 < nkt) { SB_UNIT(j + 2, c, 0); SB_UNIT(j + 2, c, 1); }
    __builtin_amdgcn_s_barrier();
    __builtin_amdgcn_s_setprio(1);
#pragma unroll
    for (int mi = 0; mi < 4; mi++)
#pragma unroll
      for (int ni = 0; ni < 4; ni++)
        acc[mi + 4][ni] = __builtin_amdgcn_mfma_f32_16x16x32_bf16(afh[mi], bf0[ni],
                                                                  acc[mi + 4][ni], 0, 0, 0);
    __builtin_amdgcn_s_setprio(0);
    __builtin_amdgcn_s_barrier();

    // ---- phase 3: af[4-7] k1 ; stage B(j+2) units 2,3 ; boundary wait ----
#pragma unroll
    for (int mi = 0; mi < 4; mi++)
      afh[mi] = *(const bf16x8*)&Ac[ar0 + (mi + 4) * 1024 + kc1];
    if (j + 2 < nkt) { SB_UNIT(j + 2, c, 2); SB_UNIT(j + 2, c, 3); }
    __builtin_amdgcn_s_barrier();
    __builtin_amdgcn_s_setprio(1);
#pragma unroll
    for (int mi = 0; mi < 4; mi++)
#pragma unroll
      for (int ni = 0; ni < 4; ni++)
        acc[mi + 4][ni] = __builtin_amdgcn_mfma_f32_16x16x32_bf16(afh[mi], bf1[ni],
                                                                  acc[mi + 4][ni], 0, 0, 0);
    __builtin_amdgcn_s_setprio(0);
    if (j + 2 < nkt) asm volatile("s_waitcnt vmcnt(4)" ::: "memory");
    else asm volatile("s_waitcnt vmcnt(0)" ::: "memory");
    __builtin_amdgcn_s_barrier();
  }
#undef SA_UNIT
#undef SB_UNIT

  // epilogue: C[row][col], row = bm+wm*128+mi*16+fq*4+r, col = bn+wn*64+ni*16+fm
#pragma unroll
  for (int ni = 0; ni < 4; ni++) {
    const int col = bn + wn * 64 + ni * 16 + fm;
    const float bvv = bias[col];
#pragma unroll
    for (int mi = 0; mi < 8; mi++)
#pragma unroll
      for (int r = 0; r < 4; r++) {
        const int row = bm + wm * 128 + mi * 16 + fq * 4 + r;
        const float val = acc[mi][ni][r] + bvv;
        if (out_f32) ((float*)Cv)[(size_t)row * N + col] = val;
        else ((__bf16*)Cv)[(size_t)row * N + col] = (__bf16)val;
      }
  }
}

// ---------------- V transpose: QKV cols[2048:3072) -> Vt[B,H,DK,T] ----------------
__global__ __launch_bounds__(256)
void transpose_v(const __bf16* __restrict__ QKV, __bf16* __restrict__ Vt) {
  const int tt = blockIdx.x;
  const int bh = blockIdx.y;
  const int b = bh >> 4, h = bh & 15;
  __shared__ __bf16 tile[64 * 68];
  const int t = threadIdx.x;
#pragma unroll
  for (int i = 0; i < 16; i++) {
    int e = i * 256 + t;
    int tok = e >> 6, dk = e & 63;
    tile[tok * 68 + dk] =
        QKV[((size_t)b * 2048 + tt * 64 + tok) * 3072 + 2048 + h * 64 + dk];
  }
  __syncthreads();
#pragma unroll
  for (int i = 0; i < 16; i++) {
    int e = i * 256 + t;
    int dk = e >> 6, tok = e & 63;
    Vt[((size_t)bh * 64 + dk) * 2048 + tt * 64 + tok] = tile[tok * 68 + dk];
  }
}

// ---------------- flash attention, causal, DK=64 (unchanged from r6) ----------------
__global__ __launch_bounds__(512)
void flash_attn(const __bf16* __restrict__ QKV, const __bf16* __restrict__ Vt,
                __bf16* __restrict__ O) {
  const int y = blockIdx.y;            // 0..7
  const int p = (y < 4) ? y : 11 - y;  // pair class 0..7
  const int qhi = 15 - p, qlo = p;     // 128-row tile indices
  const int bh = blockIdx.x;
  const int b = bh >> 4, h = bh & 15;
  __shared__ __align__(16) __bf16 Ks[2][64 * 64];
  __shared__ __align__(16) __bf16 Vs[2][64 * 64];
  const int t = threadIdx.x, lane = t & 63, wave = t >> 6;  // wave 0..7
  const int fm = lane & 15, fq = lane >> 4;
  const int tok0 = t >> 3;  // 0..63: full 64-row tile in ONE load per tensor
  const int csw = ((t & 7) ^ (tok0 & 7)) << 3;  // elems
  const int swb = (fm & 7) << 4;
  const int rb0 = (((fq << 4)) ^ swb) >> 1;       // elems
  const int rb1 = ((64 + (fq << 4)) ^ swb) >> 1;  // elems
  int voff[4];
#pragma unroll
  for (int nt = 0; nt < 4; nt++)
    voff[nt] = (((((nt << 1) | (fq >> 1))) ^ (fm & 7)) << 3) | ((fq & 1) << 2);

  const size_t kbase = ((size_t)b * 2048) * 3072 + 1024 + h * 64;
  const size_t vbase = (size_t)bh * 64 * 2048;
  const int nkt = 2 * qhi + 2;
  const int qmin[2] = {qhi * 128 + wave * 16, qlo * 128 + wave * 16};
  const float SC = 0.18033688011112042f;    // log2(e)/sqrt(64)
  const float THR_RAW = 44.3614195558365f;  // 8 / SC

  bf16x8 qf[2][2];
#pragma unroll
  for (int mi = 0; mi < 2; mi++) {
    const size_t qrow = ((size_t)b * 2048 + qmin[mi] + fm) * 3072 + h * 64;
    qf[mi][0] = *(const bf16x8*)&QKV[qrow + fq * 8];
    qf[mi][1] = *(const bf16x8*)&QKV[qrow + 32 + fq * 8];
  }

  const short4v ones4 = {(short)0x3F80, (short)0x3F80, (short)0x3F80, (short)0x3F80};

  f32x4 o_acc[2][4] = {};
  float m_i[2] = {-1e30f, -1e30f}, l_i[2] = {0.f, 0.f};

#define STAGE(KT, BUF)                                                          \
  {                                                                             \
    const int kb2 = (KT) * 64;                                                  \
    load_lds16(&QKV[kbase + (size_t)(kb2 + tok0) * 3072 + csw],                 \
               &Ks[BUF][t * 8]);                                                \
    load_lds16(&Vt[vbase + (size_t)tok0 * 2048 + kb2 + csw],                    \
               &Vs[BUF][t * 8]);                                                \
  }

  STAGE(0, 0);
  __syncthreads();  // drain + visibility for tile 0
  int cur = 0;

  for (int kt = 0; kt < nkt; kt++) {
    const int kb = kt * 64;
    if (kt + 1 < nkt) STAGE(kt + 1, cur ^ 1);  // flies across this compute

    const bool act0 = (kb <= qmin[0] + 15);
    const bool act1 = (kb <= qmin[1] + 15);
    if (act0) {
      const __bf16* Kc = Ks[cur];
      const __bf16* Vc = Vs[cur];

      f32x4 s[2][4];
      __builtin_amdgcn_s_setprio(1);
#pragma unroll
      for (int nt = 0; nt < 4; nt++) {
        const bf16x8 kf0 = *(const bf16x8*)&Kc[(nt * 16 + fm) * 64 + rb0];
        const bf16x8 kf1 = *(const bf16x8*)&Kc[(nt * 16 + fm) * 64 + rb1];
        {
          f32x4 z = {};
          z = __builtin_amdgcn_mfma_f32_16x16x32_bf16(kf0, qf[0][0], z, 0, 0, 0);
          z = __builtin_amdgcn_mfma_f32_16x16x32_bf16(kf1, qf[0][1], z, 0, 0, 0);
          s[0][nt] = z;
        }
        if (act1) {
          f32x4 z = {};
          z = __builtin_amdgcn_mfma_f32_16x16x32_bf16(kf0, qf[1][0], z, 0, 0, 0);
          z = __builtin_amdgcn_mfma_f32_16x16x32_bf16(kf1, qf[1][1], z, 0, 0, 0);
          s[1][nt] = z;
        }
      }
      __builtin_amdgcn_s_setprio(0);

#pragma unroll
      for (int mi = 0; mi < 2; mi++) {
        if (mi == 1 && !act1) continue;
        if (kb + 63 > qmin[mi]) {
          const int qq = qmin[mi] + fm;
#pragma unroll
          for (int nt = 0; nt < 4; nt++) {
            const int kk = kb + nt * 16 + fq * 4;
#pragma unroll
            for (int r = 0; r < 4; r++)
              if (kk + r > qq) s[mi][nt][r] = -1e30f;
          }
        }
      }

#pragma unroll
      for (int mi = 0; mi < 2; mi++) {
        if (mi == 1 && !act1) continue;

        float a = fmaxf(fmaxf(s[mi][0][0], s[mi][0][1]),
                        fmaxf(s[mi][0][2], s[mi][0][3]));
#pragma unroll
        for (int nt = 1; nt < 4; nt++)
          a = fmaxf(a, fmaxf(fmaxf(s[mi][nt][0], s[mi][nt][1]),
                             fmaxf(s[mi][nt][2], s[mi][nt][3])));
        a = fmaxf(a, __shfl_xor(a, 16, 64));
        a = fmaxf(a, __shfl_xor(a, 32, 64));
        const float rmax = a;

        if (!__all(rmax - m_i[mi] <= THR_RAW)) {
          const float mn = fmaxf(m_i[mi], rmax);
          const float al = exp2f(SC * (m_i[mi] - mn));
          m_i[mi] = mn;
          l_i[mi] *= al;
#pragma unroll
          for (int dt = 0; dt < 4; dt++)
#pragma unroll
            for (int r = 0; r < 4; r++) o_acc[mi][dt][r] *= al;
        }

        short4v pb[4];
        const float msc = -SC * m_i[mi];
#pragma unroll
        for (int nt = 0; nt < 4; nt++) {
          const float p0 = exp2f(fmaf(s[mi][nt][0], SC, msc));
          const float p1 = exp2f(fmaf(s[mi][nt][1], SC, msc));
          const float p2 = exp2f(fmaf(s[mi][nt][2], SC, msc));
          const float p3 = exp2f(fmaf(s[mi][nt][3], SC, msc));
          pb[nt] = mk4(pack_bf2(p0, p1), pack_bf2(p2, p3));
        }

        f32x4 rs = {};
#pragma unroll
        for (int nt = 0; nt < 4; nt++) rs = mfma16(ones4, pb[nt], rs);

        __builtin_amdgcn_s_setprio(1);
#pragma unroll
        for (int dt = 0; dt < 4; dt++) {
          const int rowb = (dt * 16 + fm) * 64;
          f32x4 o = o_acc[mi][dt];
#pragma unroll
          for (int nt = 0; nt < 4; nt++) {
            const short4v vf = *(const short4v*)&Vc[rowb + voff[nt]];
            o = mfma16(vf, pb[nt], o);
          }
          o_acc[mi][dt] = o;
        }
        __builtin_amdgcn_s_setprio(0);

        l_i[mi] += rs[0];
      }
    }

    __syncthreads();  // next tile staged + all reads of buf[cur] complete
    cur ^= 1;
  }

#pragma unroll
  for (int mi = 0; mi < 2; mi++) {
    const float linv = 1.f / l_i[mi];
    const size_t orow = (size_t)b * 2048 + qmin[mi] + fm;
#pragma unroll
    for (int dt = 0; dt < 4; dt++) {
      bf16x4 w;
#pragma unroll
      for (int r = 0; r < 4; r++) w[r] = (__bf16)(o_acc[mi][dt][r] * linv);
      *(bf16x4*)&O[orow * 1024 + h * 64 + dt * 16 + fq * 4] = w;
    }
  }
#undef STAGE
}

// ---------------- launch ----------------
extern "C" void kernel_launch(void* const* d_in, const int* in_sizes, int n_in,
                              void* d_out, int out_size, void* d_ws, size_t ws_size,
                              hipStream_t stream) {
  const float* x = (const float*)d_in[0];
  const float* Wq = (const float*)d_in[1];
  const float* bq = (const float*)d_in[2];
  const float* Wk = (const float*)d_in[3];
  const float* bk = (const float*)d_in[4];
  const float* Wv = (const float*)d_in[5];
  const float* bv = (const float*)d_in[6];
  const float* Wo = (const float*)d_in[7];
  const float* bo = (const float*)d_in[8];

  // workspace layout (bytes), ~92 MB total
  char* ws = (char*)d_ws;
  __bf16* Bt1 = (__bf16*)(ws);               // [3072,1024] WqT|WkT|WvT  (6 MB)
  __bf16* Bt2 = (__bf16*)(ws + 6291456);     // [1024,1024] WoT          (2 MB)
  float* bqkv = (float*)(ws + 8388608);      // [3072] f32
  float* bo_f = (float*)(ws + 8400896);      // [1024] f32
  __bf16* QKV = (__bf16*)(ws + 8405504);     // [8192,3072]              (48 MB)
  __bf16* Vt = (__bf16*)(ws + 58737152);     // [4,16,64,2048]           (16 MB)
  __bf16* Xb = (__bf16*)(ws + 75514368);     // [8192,1024] bf16 x       (16 MB)
  __bf16* Ow = Xb;  // Xb dead after gemm1; flash output reuses the region

  hipLaunchKernelGGL(convert_x, dim3(4096), dim3(256), 0, stream, x, Xb);
  hipLaunchKernelGGL(prep_weights, dim3(16, 16, 4), dim3(256), 0, stream,
                     Wq, Wk, Wv, Wo, bq, bk, bv, bo, Bt1, Bt2, bqkv, bo_f);
  hipLaunchKernelGGL(gemm256, dim3(32, 12), dim3(512), 0, stream,
                     Xb, Bt1, bqkv, (void*)QKV, 0, 8192, 3072, 1024);
  hipLaunchKernelGGL(transpose_v, dim3(32, 64), dim3(256), 0, stream, QKV, Vt);
  hipLaunchKernelGGL(flash_attn, dim3(64, 8), dim3(512), 0, stream, QKV, Vt, Ow);
  hipLaunchKernelGGL(gemm256, dim3(32, 4), dim3(512), 0, stream,
                     Ow, Bt2, bo_f, d_out, 1, 8192, 1024, 1024);
}

// Round 10
// 299.399 us; speedup vs baseline: 1.1123x; 1.0806x over previous
//
#include <hip/hip_runtime.h>
#include <stdint.h>
#include <math.h>

// B=4, T=2048, D=1024, H=16, DK=64.
// Inputs fp32, output fp32; internal compute bf16 MFMA + fp32 accum.
typedef __attribute__((ext_vector_type(8))) __bf16 bf16x8;
typedef __attribute__((ext_vector_type(4))) __bf16 bf16x4;
typedef __attribute__((ext_vector_type(4))) float f32x4;
typedef __attribute__((ext_vector_type(4))) short short4v;

__device__ __forceinline__ void load_lds16(const void* g, void* l) {
  __builtin_amdgcn_global_load_lds((__attribute__((address_space(1))) void*)(g),
                                   (__attribute__((address_space(3))) void*)(l),
                                   16, 0, 0);
}

__device__ __forceinline__ uint32_t pack_bf2(float a, float b) {
  union { __bf16 h; uint16_t u; } x, y;
  x.h = (__bf16)a; y.h = (__bf16)b;
  return (uint32_t)x.u | ((uint32_t)y.u << 16);
}

__device__ __forceinline__ short4v mk4(uint32_t lo, uint32_t hi) {
  union { uint32_t d[2]; short4v v; } u;
  u.d[0] = lo; u.d[1] = hi;
  return u.v;
}

// 16x16x16 bf16 MFMA: B-operand k-layout (k = fq*4+j) matches the S^T
// C-layout exactly -> P feeds PV with ZERO cross-lane ops.
__device__ __forceinline__ f32x4 mfma16(short4v a, short4v b, f32x4 c) {
#if defined(__has_builtin) && __has_builtin(__builtin_amdgcn_mfma_f32_16x16x16bf16_1k)
  return __builtin_amdgcn_mfma_f32_16x16x16bf16_1k(a, b, c, 0, 0, 0);
#else
  asm volatile("v_mfma_f32_16x16x16_bf16 %0, %1, %2, %0"
               : "+v"(c) : "v"(a), "v"(b));
  return c;
#endif
}

// ---------------- x (fp32) -> bf16 canonical copy ----------------
__global__ __launch_bounds__(256)
void convert_x(const float* __restrict__ xf, __bf16* __restrict__ xb) {
  const size_t i = ((size_t)blockIdx.x * 256 + threadIdx.x) * 8;  // n = 8388608 exact
  const float4 u0 = *(const float4*)(xf + i);
  const float4 u1 = *(const float4*)(xf + i + 4);
  bf16x8 v;
  v[0] = (__bf16)u0.x; v[1] = (__bf16)u0.y; v[2] = (__bf16)u0.z; v[3] = (__bf16)u0.w;
  v[4] = (__bf16)u1.x; v[5] = (__bf16)u1.y; v[6] = (__bf16)u1.z; v[7] = (__bf16)u1.w;
  *(bf16x8*)&xb[i] = v;
}

// ---------------- weight transpose ([K,N] fp32 -> [N,K] bf16) + bias pack ----------------
__global__ __launch_bounds__(256)
void prep_weights(const float* __restrict__ Wq, const float* __restrict__ Wk,
                  const float* __restrict__ Wv, const float* __restrict__ Wo,
                  const float* __restrict__ bq, const float* __restrict__ bk,
                  const float* __restrict__ bv, const float* __restrict__ bo,
                  __bf16* __restrict__ Bt1, __bf16* __restrict__ Bt2,
                  float* __restrict__ bqkv, float* __restrict__ bo_f) {
  const int m = blockIdx.z;  // 0=Wq 1=Wk 2=Wv 3=Wo
  const float* W = (m == 0) ? Wq : (m == 1) ? Wk : (m == 2) ? Wv : Wo;
  __bf16* Out = (m == 3) ? Bt2 : Bt1 + (size_t)m * 1024 * 1024;
  const int kt = blockIdx.x * 64, nt = blockIdx.y * 64;
  __shared__ __bf16 tile[64 * 68];
  const int t = threadIdx.x;
#pragma unroll
  for (int i = 0; i < 16; i++) {
    int e = i * 256 + t;
    int r = e >> 6, c = e & 63;
    tile[r * 68 + c] = (__bf16)W[(size_t)(kt + r) * 1024 + nt + c];
  }
  __syncthreads();
#pragma unroll
  for (int i = 0; i < 16; i++) {
    int e = i * 256 + t;
    int r = e >> 6, c = e & 63;
    Out[(size_t)(nt + r) * 1024 + kt + c] = tile[c * 68 + r];
  }
  if (blockIdx.x == 0 && blockIdx.y == 0) {
    if (m < 3) {
      const float* bsrc = (m == 0) ? bq : (m == 1) ? bk : bv;
      for (int i = t; i < 1024; i += 256) bqkv[m * 1024 + i] = bsrc[i];
    } else {
      for (int i = t; i < 1024; i += 256) bo_f[i] = bo[i];
    }
  }
}

// ---------------- GEMM 256x128, 3-buffer deep pipeline ----------------
// C[M,N] = A[M,K] @ Bt[N,K]^T + bias. 512 thr / 8 waves (4M x 2N), per-wave
// 64x64 (acc 4x4 f32x4 = 64 VGPR), BK=64. LDS = 3 x (256+128)x64x2B = 144KB.
// DEEP PIPELINE: during tile j, stage tile j+2 into buf (j+2)%3 -- that
// buffer holds tile j-1, whose reads closed at the boundary barrier before
// tile j => NO intra-buffer region hazard. Steady state: 6 loads always in
// flight; s_waitcnt vmcnt(6) at tile boundaries ONLY (never 0 in the loop).
// 2 phases/tile: {8 ds_read_b128 || 3 gload_lds -> s_barrier -> 16 MFMA ->
// s_barrier}. XOR-swizzle via pre-swizzled source (rule 21).
// Geometry: gemm1 grid (32,24)=768 = 3 EXACT rounds of 256 CUs; gemm2
// (32,8)=256 = one full round (r8's 256sq: 1.5-round tail / half-chip).
// Fused V-transpose: blocks with bn>=2048 (block-uniform) write V directly
// to Vt[b,h,dk,tok] (bf16x4 along tok) and skip QKV -- transpose_v deleted.
__global__ __launch_bounds__(512)
void gemm256(const __bf16* __restrict__ A, const __bf16* __restrict__ Bt,
             const float* __restrict__ bias, void* __restrict__ Cv,
             __bf16* __restrict__ Vt, int out_f32, int M, int N, int K) {
  __shared__ __align__(16) __bf16 As[3 * 256 * 64];
  __shared__ __align__(16) __bf16 Bs[3 * 128 * 64];
  const int t = threadIdx.x, lane = t & 63, wave = t >> 6;
  const int wm = wave >> 1, wn = wave & 1;  // 4M x 2N
  const int fm = lane & 15, fq = lane >> 4;
  const int bm = blockIdx.x * 256, bn = blockIdx.y * 128;

  // staging unit = 64 rows x 64 k (one gload_lds: 512 thr x 16B).
  const int srow = t >> 3;
  const int scol = ((t & 7) ^ (srow & 7)) << 3;  // pre-swizzled source elems
  const __bf16* Ag = A + (size_t)(bm + srow) * K + scol;
  const __bf16* Bg = Bt + (size_t)(bn + srow) * K + scol;

  // read-side swizzled column offsets (elems); frag rows === fm (mod 8)
  const int kc0 = ((fq ^ (fm & 7)) << 3);
  const int kc1 = (((4 | fq) ^ (fm & 7)) << 3);
  const int ar0 = (wm * 64 + fm) * 64;
  const int br0 = (wn * 64 + fm) * 64;

  f32x4 acc[4][4] = {};
  const int nkt = K >> 6;

#define SA(TT, BUF, U)                                                     \
  load_lds16(Ag + (size_t)(U) * 64 * K + (size_t)(TT) * 64,                \
             &As[(BUF) * 16384 + (U) * 4096 + t * 8])
#define SB(TT, BUF, U)                                                     \
  load_lds16(Bg + (size_t)(U) * 64 * K + (size_t)(TT) * 64,                \
             &Bs[(BUF) * 8192 + (U) * 4096 + t * 8])

  // prologue: stage tiles 0 and 1 (6 units each); wait tile0, tile1 flies
  SA(0, 0, 0); SA(0, 0, 1); SA(0, 0, 2); SA(0, 0, 3); SB(0, 0, 0); SB(0, 0, 1);
  if (nkt > 1) {
    SA(1, 1, 0); SA(1, 1, 1); SA(1, 1, 2); SA(1, 1, 3); SB(1, 1, 0); SB(1, 1, 1);
    asm volatile("s_waitcnt vmcnt(6)" ::: "memory");
  } else {
    asm volatile("s_waitcnt vmcnt(0)" ::: "memory");
  }
  __builtin_amdgcn_s_barrier();

  int c = 0, c2 = 2;
  for (int j = 0; j < nkt; ++j) {
    const __bf16* Ac = &As[c * 16384];
    const __bf16* Bc = &Bs[c * 8192];
    bf16x8 af[4], bf[4];

    // ---- phase 0: k-slice 0 ; stage A(j+2) units 0,1,2 ----
#pragma unroll
    for (int mi = 0; mi < 4; mi++) af[mi] = *(const bf16x8*)&Ac[ar0 + mi * 1024 + kc0];
#pragma unroll
    for (int ni = 0; ni < 4; ni++) bf[ni] = *(const bf16x8*)&Bc[br0 + ni * 1024 + kc0];
    if (j + 2 < nkt) { SA(j + 2, c2, 0); SA(j + 2, c2, 1); SA(j + 2, c2, 2); }
    __builtin_amdgcn_s_barrier();
    __builtin_amdgcn_s_setprio(1);
#pragma unroll
    for (int mi = 0; mi < 4; mi++)
#pragma unroll
      for (int ni = 0; ni < 4; ni++)
        acc[mi][ni] = __builtin_amdgcn_mfma_f32_16x16x32_bf16(af[mi], bf[ni],
                                                              acc[mi][ni], 0, 0, 0);
    __builtin_amdgcn_s_setprio(0);
    __builtin_amdgcn_s_barrier();

    // ---- phase 1: k-slice 1 ; stage A(j+2) unit 3 + B(j+2) units 0,1 ----
#pragma unroll
    for (int mi = 0; mi < 4; mi++) af[mi] = *(const bf16x8*)&Ac[ar0 + mi * 1024 + kc1];
#pragma unroll
    for (int ni = 0; ni < 4; ni++) bf[ni] = *(const bf16x8*)&Bc[br0 + ni * 1024 + kc1];
    if (j + 2 < nkt) { SA(j + 2, c2, 3); SB(j + 2, c2, 0); SB(j + 2, c2, 1); }
    __builtin_amdgcn_s_barrier();
    __builtin_amdgcn_s_setprio(1);
#pragma unroll
    for (int mi = 0; mi < 4; mi++)
#pragma unroll
      for (int ni = 0; ni < 4; ni++)
        acc[mi][ni] = __builtin_amdgcn_mfma_f32_16x16x32_bf16(af[mi], bf[ni],
                                                              acc[mi][ni], 0, 0, 0);
    __builtin_amdgcn_s_setprio(0);

    // boundary: land tile j+1 (leave tile j+2's 6 loads flying)
    if (j + 2 < nkt) asm volatile("s_waitcnt vmcnt(6)" ::: "memory");
    else if (j + 1 < nkt) asm volatile("s_waitcnt vmcnt(0)" ::: "memory");
    __builtin_amdgcn_s_barrier();

    c = (c == 2) ? 0 : c + 1;
    c2 = (c2 == 2) ? 0 : c2 + 1;
  }
#undef SA
#undef SB

  // epilogue: C row = bm + wm*64 + mi*16 + fq*4 + r, col = bn + wn*64 + ni*16 + fm
  const bool v_mode = (Vt != nullptr) && (bn >= 2048);
#pragma unroll
  for (int ni = 0; ni < 4; ni++) {
    const int col = bn + wn * 64 + ni * 16 + fm;
    const float bvv = bias[col];
    if (v_mode) {
      const int vcol = col - 2048;
      const int hh = vcol >> 6, dk = vcol & 63;
#pragma unroll
      for (int mi = 0; mi < 4; mi++) {
        const int row0 = bm + wm * 64 + mi * 16 + fq * 4;
        const int b = row0 >> 11, tok = row0 & 2047;
        bf16x4 w;
#pragma unroll
        for (int r = 0; r < 4; r++) w[r] = (__bf16)(acc[mi][ni][r] + bvv);
        *(bf16x4*)&Vt[(((size_t)b * 16 + hh) * 64 + dk) * 2048 + tok] = w;
      }
    } else {
#pragma unroll
      for (int mi = 0; mi < 4; mi++)
#pragma unroll
        for (int r = 0; r < 4; r++) {
          const int row = bm + wm * 64 + mi * 16 + fq * 4 + r;
          const float val = acc[mi][ni][r] + bvv;
          if (out_f32) ((float*)Cv)[(size_t)row * N + col] = val;
          else ((__bf16*)Cv)[(size_t)row * N + col] = (__bf16)val;
        }
    }
  }
}

// ---------------- flash attention, causal, DK=64 (unchanged from r6) ----------------
__global__ __launch_bounds__(512)
void flash_attn(const __bf16* __restrict__ QKV, const __bf16* __restrict__ Vt,
                __bf16* __restrict__ O) {
  const int y = blockIdx.y;            // 0..7
  const int p = (y < 4) ? y : 11 - y;  // pair class 0..7
  const int qhi = 15 - p, qlo = p;     // 128-row tile indices
  const int bh = blockIdx.x;
  const int b = bh >> 4, h = bh & 15;
  __shared__ __align__(16) __bf16 Ks[2][64 * 64];
  __shared__ __align__(16) __bf16 Vs[2][64 * 64];
  const int t = threadIdx.x, lane = t & 63, wave = t >> 6;  // wave 0..7
  const int fm = lane & 15, fq = lane >> 4;
  const int tok0 = t >> 3;  // 0..63: full 64-row tile in ONE load per tensor
  const int csw = ((t & 7) ^ (tok0 & 7)) << 3;  // elems
  const int swb = (fm & 7) << 4;
  const int rb0 = (((fq << 4)) ^ swb) >> 1;       // elems
  const int rb1 = ((64 + (fq << 4)) ^ swb) >> 1;  // elems
  int voff[4];
#pragma unroll
  for (int nt = 0; nt < 4; nt++)
    voff[nt] = (((((nt << 1) | (fq >> 1))) ^ (fm & 7)) << 3) | ((fq & 1) << 2);

  const size_t kbase = ((size_t)b * 2048) * 3072 + 1024 + h * 64;
  const size_t vbase = (size_t)bh * 64 * 2048;
  const int nkt = 2 * qhi + 2;
  const int qmin[2] = {qhi * 128 + wave * 16, qlo * 128 + wave * 16};
  const float SC = 0.18033688011112042f;    // log2(e)/sqrt(64)
  const float THR_RAW = 44.3614195558365f;  // 8 / SC

  bf16x8 qf[2][2];
#pragma unroll
  for (int mi = 0; mi < 2; mi++) {
    const size_t qrow = ((size_t)b * 2048 + qmin[mi] + fm) * 3072 + h * 64;
    qf[mi][0] = *(const bf16x8*)&QKV[qrow + fq * 8];
    qf[mi][1] = *(const bf16x8*)&QKV[qrow + 32 + fq * 8];
  }

  const short4v ones4 = {(short)0x3F80, (short)0x3F80, (short)0x3F80, (short)0x3F80};

  f32x4 o_acc[2][4] = {};
  float m_i[2] = {-1e30f, -1e30f}, l_i[2] = {0.f, 0.f};

#define STAGE(KT, BUF)                                                          \
  {                                                                             \
    const int kb2 = (KT) * 64;                                                  \
    load_lds16(&QKV[kbase + (size_t)(kb2 + tok0) * 3072 + csw],                 \
               &Ks[BUF][t * 8]);                                                \
    load_lds16(&Vt[vbase + (size_t)tok0 * 2048 + kb2 + csw],                    \
               &Vs[BUF][t * 8]);                                                \
  }

  STAGE(0, 0);
  __syncthreads();  // drain + visibility for tile 0
  int cur = 0;

  for (int kt = 0; kt < nkt; kt++) {
    const int kb = kt * 64;
    if (kt + 1 < nkt) STAGE(kt + 1, cur ^ 1);  // flies across this compute

    const bool act0 = (kb <= qmin[0] + 15);
    const bool act1 = (kb <= qmin[1] + 15);
    if (act0) {
      const __bf16* Kc = Ks[cur];
      const __bf16* Vc = Vs[cur];

      f32x4 s[2][4];
      __builtin_amdgcn_s_setprio(1);
#pragma unroll
      for (int nt = 0; nt < 4; nt++) {
        const bf16x8 kf0 = *(const bf16x8*)&Kc[(nt * 16 + fm) * 64 + rb0];
        const bf16x8 kf1 = *(const bf16x8*)&Kc[(nt * 16 + fm) * 64 + rb1];
        {
          f32x4 z = {};
          z = __builtin_amdgcn_mfma_f32_16x16x32_bf16(kf0, qf[0][0], z, 0, 0, 0);
          z = __builtin_amdgcn_mfma_f32_16x16x32_bf16(kf1, qf[0][1], z, 0, 0, 0);
          s[0][nt] = z;
        }
        if (act1) {
          f32x4 z = {};
          z = __builtin_amdgcn_mfma_f32_16x16x32_bf16(kf0, qf[1][0], z, 0, 0, 0);
          z = __builtin_amdgcn_mfma_f32_16x16x32_bf16(kf1, qf[1][1], z, 0, 0, 0);
          s[1][nt] = z;
        }
      }
      __builtin_amdgcn_s_setprio(0);

#pragma unroll
      for (int mi = 0; mi < 2; mi++) {
        if (mi == 1 && !act1) continue;
        if (kb + 63 > qmin[mi]) {
          const int qq = qmin[mi] + fm;
#pragma unroll
          for (int nt = 0; nt < 4; nt++) {
            const int kk = kb + nt * 16 + fq * 4;
#pragma unroll
            for (int r = 0; r < 4; r++)
              if (kk + r > qq) s[mi][nt][r] = -1e30f;
          }
        }
      }

#pragma unroll
      for (int mi = 0; mi < 2; mi++) {
        if (mi == 1 && !act1) continue;

        float a = fmaxf(fmaxf(s[mi][0][0], s[mi][0][1]),
                        fmaxf(s[mi][0][2], s[mi][0][3]));
#pragma unroll
        for (int nt = 1; nt < 4; nt++)
          a = fmaxf(a, fmaxf(fmaxf(s[mi][nt][0], s[mi][nt][1]),
                             fmaxf(s[mi][nt][2], s[mi][nt][3])));
        a = fmaxf(a, __shfl_xor(a, 16, 64));
        a = fmaxf(a, __shfl_xor(a, 32, 64));
        const float rmax = a;

        if (!__all(rmax - m_i[mi] <= THR_RAW)) {
          const float mn = fmaxf(m_i[mi], rmax);
          const float al = exp2f(SC * (m_i[mi] - mn));
          m_i[mi] = mn;
          l_i[mi] *= al;
#pragma unroll
          for (int dt = 0; dt < 4; dt++)
#pragma unroll
            for (int r = 0; r < 4; r++) o_acc[mi][dt][r] *= al;
        }

        short4v pb[4];
        const float msc = -SC * m_i[mi];
#pragma unroll
        for (int nt = 0; nt < 4; nt++) {
          const float p0 = exp2f(fmaf(s[mi][nt][0], SC, msc));
          const float p1 = exp2f(fmaf(s[mi][nt][1], SC, msc));
          const float p2 = exp2f(fmaf(s[mi][nt][2], SC, msc));
          const float p3 = exp2f(fmaf(s[mi][nt][3], SC, msc));
          pb[nt] = mk4(pack_bf2(p0, p1), pack_bf2(p2, p3));
        }

        f32x4 rs = {};
#pragma unroll
        for (int nt = 0; nt < 4; nt++) rs = mfma16(ones4, pb[nt], rs);

        __builtin_amdgcn_s_setprio(1);
#pragma unroll
        for (int dt = 0; dt < 4; dt++) {
          const int rowb = (dt * 16 + fm) * 64;
          f32x4 o = o_acc[mi][dt];
#pragma unroll
          for (int nt = 0; nt < 4; nt++) {
            const short4v vf = *(const short4v*)&Vc[rowb + voff[nt]];
            o = mfma16(vf, pb[nt], o);
          }
          o_acc[mi][dt] = o;
        }
        __builtin_amdgcn_s_setprio(0);

        l_i[mi] += rs[0];
      }
    }

    __syncthreads();  // next tile staged + all reads of buf[cur] complete
    cur ^= 1;
  }

#pragma unroll
  for (int mi = 0; mi < 2; mi++) {
    const float linv = 1.f / l_i[mi];
    const size_t orow = (size_t)b * 2048 + qmin[mi] + fm;
#pragma unroll
    for (int dt = 0; dt < 4; dt++) {
      bf16x4 w;
#pragma unroll
      for (int r = 0; r < 4; r++) w[r] = (__bf16)(o_acc[mi][dt][r] * linv);
      *(bf16x4*)&O[orow * 1024 + h * 64 + dt * 16 + fq * 4] = w;
    }
  }
#undef STAGE
}

// ---------------- launch ----------------
extern "C" void kernel_launch(void* const* d_in, const int* in_sizes, int n_in,
                              void* d_out, int out_size, void* d_ws, size_t ws_size,
                              hipStream_t stream) {
  const float* x = (const float*)d_in[0];
  const float* Wq = (const float*)d_in[1];
  const float* bq = (const float*)d_in[2];
  const float* Wk = (const float*)d_in[3];
  const float* bk = (const float*)d_in[4];
  const float* Wv = (const float*)d_in[5];
  const float* bv = (const float*)d_in[6];
  const float* Wo = (const float*)d_in[7];
  const float* bo = (const float*)d_in[8];

  // workspace layout (bytes), ~92 MB total
  char* ws = (char*)d_ws;
  __bf16* Bt1 = (__bf16*)(ws);               // [3072,1024] WqT|WkT|WvT  (6 MB)
  __bf16* Bt2 = (__bf16*)(ws + 6291456);     // [1024,1024] WoT          (2 MB)
  float* bqkv = (float*)(ws + 8388608);      // [3072] f32
  float* bo_f = (float*)(ws + 8400896);      // [1024] f32
  __bf16* QKV = (__bf16*)(ws + 8405504);     // [8192,3072] (V cols unused) (48 MB)
  __bf16* Vt = (__bf16*)(ws + 58737152);     // [4,16,64,2048]           (16 MB)
  __bf16* Xb = (__bf16*)(ws + 75514368);     // [8192,1024] bf16 x       (16 MB)
  __bf16* Ow = Xb;  // Xb dead after gemm1; flash output reuses the region

  hipLaunchKernelGGL(convert_x, dim3(4096), dim3(256), 0, stream, x, Xb);
  hipLaunchKernelGGL(prep_weights, dim3(16, 16, 4), dim3(256), 0, stream,
                     Wq, Wk, Wv, Wo, bq, bk, bv, bo, Bt1, Bt2, bqkv, bo_f);
  // gemm1: Q/K -> QKV cols [0,2048); V -> Vt directly (fused transpose)
  hipLaunchKernelGGL(gemm256, dim3(32, 24), dim3(512), 0, stream,
                     Xb, Bt1, bqkv, (void*)QKV, Vt, 0, 8192, 3072, 1024);
  hipLaunchKernelGGL(flash_attn, dim3(64, 8), dim3(512), 0, stream, QKV, Vt, Ow);
  hipLaunchKernelGGL(gemm256, dim3(32, 8), dim3(512), 0, stream,
                     Ow, Bt2, bo_f, d_out, (__bf16*)nullptr, 1, 8192, 1024, 1024);
}